// Round 3
// baseline (3414.494 us; speedup 1.0000x reference)
//
#include <hip/hip_runtime.h>
#include <math.h>

// ARC / DRAW-style attention LSTM. B=4096 items, 16 steps, HID=128, 8x8 glimpse.
// Round 2: deliberately-simple correctness probe. No wave-level tricks, no LDS
// aliasing, explicit barriers between every phase, normalized filters
// materialized (reference order), fp32 stepwise math with double-evaluated
// transcendentals rounded to fp32 (mimics correctly-rounded libm fp32).
#define NITEMS 4
#define NTHREADS 256

struct SM {
    float h[NITEMS][128];
    float c[NITEMS][128];
    float gp[NITEMS][3];
    float aux[NITEMS][5];      // delt, gam, pg(=pi*gam), ctrH, ctrW
    float S[NITEMS][2][8];     // normalizer sums (+1e-4)
    float F[NITEMS][2][8][64]; // raw then normalized in place; [bank][target][src]
    float t1[NITEMS][8][64];
    float x[NITEMS][64];
    float gates[NITEMS][512];
};

__device__ __forceinline__ float tanh_ref(float v)  { return (float)tanh((double)v); }
__device__ __forceinline__ float exp_ref(float v)   { return (float)exp((double)v); }
__device__ __forceinline__ float sigmoid_ref(float v) {
    float e = exp_ref(-v);
    return 1.0f / (1.0f + e);
}

__global__ __launch_bounds__(NTHREADS) void arc_main(
    const float* __restrict__ img,    // (B,2,64,64)
    const float* __restrict__ Wih,    // (512,64)
    const float* __restrict__ Whh,    // (512,128)
    const float* __restrict__ bih,    // (512,)
    const float* __restrict__ bhh,    // (512,)
    const float* __restrict__ Wg,     // (3,128)
    const float* __restrict__ bg,     // (3,)
    float* __restrict__ out)          // (B,128)
{
    #pragma clang fp contract(off)
    __shared__ SM sm;
    const int tid = threadIdx.x;
    const int item0 = blockIdx.x * NITEMS;

    for (int i = tid; i < NITEMS * 128; i += NTHREADS) {
        sm.h[i >> 7][i & 127] = 0.f;
        sm.c[i >> 7][i & 127] = 0.f;
    }
    __syncthreads();

    for (int t = 0; t < 16; ++t) {
        // ---- A: gp[m][r] = tanh( sum_k h[m][k]*Wg[r][k] + bg[r] ) ----
        if (tid < NITEMS * 3) {
            int m = tid / 3, r = tid % 3;
            const float* hh = sm.h[m];
            const float* w  = Wg + r * 128;
            float acc = 0.f;
            for (int k = 0; k < 128; ++k) acc = fmaf(hh[k], w[k], acc);
            acc = acc + bg[r];
            sm.gp[m][r] = tanh_ref(acc);
        }
        __syncthreads();
        // ---- A2: per-item scalars ----
        if (tid < NITEMS) {
            int m = tid;
            float g0 = sm.gp[m][0], g1 = sm.gp[m][1], g2 = sm.gp[m][2];
            float ad   = fabsf(g2);
            float t2   = 2.0f * ad;            // exact
            float e    = 1.0f - t2;            // round
            float gam  = exp_ref(e);
            float oma  = 1.0f - ad;            // round
            float delt = 8.0f * oma;           // exact (fl/tl = 8)
            float pg   = 3.14159274101257324f * gam;   // (float)pi * gammas
            float c0p  = g0 + 1.0f;
            float ctrH = (63.0f * c0p) * 0.5f; // ((fl-1)*(c+1))/2
            float c1p  = g1 + 1.0f;
            float ctrW = (63.0f * c1p) * 0.5f;
            sm.aux[m][0] = delt; sm.aux[m][1] = gam; sm.aux[m][2] = pg;
            sm.aux[m][3] = ctrH; sm.aux[m][4] = ctrW;
        }
        __syncthreads();
        // ---- B: raw filter values F[m][bank][tt][i] ----
        for (int idx = tid; idx < NITEMS * 2 * 8 * 64; idx += NTHREADS) {
            int m    = idx >> 10;
            int bank = (idx >> 9) & 1;
            int tt   = (idx >> 6) & 7;
            int i    = idx & 63;
            float delt = sm.aux[m][0], gam = sm.aux[m][1], pg = sm.aux[m][2];
            float ctr  = sm.aux[m][3 + bank];
            float gp_off = (float)tt - 3.5f;   // gpix base: arange(8) - 3.5
            float dterm  = delt * gp_off;      // round (no fma)
            float gq     = ctr + dterm;        // round
            float num    = (float)i - gq;      // round
            float d      = num / gam;          // round
            float dd     = d * d;              // round
            float opdd   = 1.0f + dd;          // round
            float den    = pg * opdd;          // round
            sm.F[m][bank][tt][i] = 1.0f / den; // round
        }
        __syncthreads();
        // ---- C1: normalizer sums, numpy pairwise-stripe order ----
        if (tid < NITEMS * 16) {
            int m = tid >> 4, bank = (tid >> 3) & 1, tt = tid & 7;
            const float* a = sm.F[m][bank][tt];
            float r0=a[0], r1=a[1], r2=a[2], r3=a[3], r4=a[4], r5=a[5], r6=a[6], r7=a[7];
            for (int i = 8; i < 64; i += 8) {
                r0 += a[i];   r1 += a[i+1]; r2 += a[i+2]; r3 += a[i+3];
                r4 += a[i+4]; r5 += a[i+5]; r6 += a[i+6]; r7 += a[i+7];
            }
            float s = ((r0 + r1) + (r2 + r3)) + ((r4 + r5) + (r6 + r7));
            sm.S[m][bank][tt] = s + 1e-4f;
        }
        __syncthreads();
        // ---- C2: normalize F in place (reference normalizes before matmuls) ----
        for (int idx = tid; idx < NITEMS * 2 * 8 * 64; idx += NTHREADS) {
            int m    = idx >> 10;
            int bank = (idx >> 9) & 1;
            int tt   = (idx >> 6) & 7;
            int i    = idx & 63;
            sm.F[m][bank][tt][i] = sm.F[m][bank][tt][i] / sm.S[m][bank][tt];
        }
        __syncthreads();
        // ---- D: t1[m][tt][w] = sum_h F[m][0][tt][h] * img[m][h][w] ----
        for (int idx = tid; idx < NITEMS * 8 * 64; idx += NTHREADS) {
            int m  = idx >> 9;
            int tt = (idx >> 6) & 7;
            int w  = idx & 63;
            const float* ip = img + (size_t)(item0 + m) * 8192 + (t & 1) * 4096;
            const float* fr = sm.F[m][0][tt];
            float acc = 0.f;
            for (int hh = 0; hh < 64; ++hh)
                acc = fmaf(fr[hh], ip[hh * 64 + w], acc);
            sm.t1[m][tt][w] = acc;
        }
        __syncthreads();
        // ---- E: x[m][tt*8+s] = sum_w t1[m][tt][w] * F[m][1][s][w] ----
        {
            int m = tid >> 6, rem = tid & 63;     // 256 threads = 4 items * 64 outputs
            int tt = rem >> 3, s = rem & 7;
            const float* tr = sm.t1[m][tt];
            const float* fw = sm.F[m][1][s];
            float acc = 0.f;
            for (int w = 0; w < 64; ++w) acc = fmaf(tr[w], fw[w], acc);
            sm.x[m][rem] = acc;
        }
        __syncthreads();
        // ---- F: gates[m][j] = ((x.Wih_j + bih_j) + h.Whh_j) + bhh_j ----
        for (int idx = tid; idx < NITEMS * 512; idx += NTHREADS) {
            int m = idx >> 9, j = idx & 511;
            const float* wi = Wih + j * 64;
            float ax = 0.f;
            for (int k = 0; k < 64; ++k) ax = fmaf(sm.x[m][k], wi[k], ax);
            const float* wh = Whh + j * 128;
            float ah = 0.f;
            for (int k = 0; k < 128; ++k) ah = fmaf(sm.h[m][k], wh[k], ah);
            sm.gates[m][j] = ((ax + bih[j]) + ah) + bhh[j];
        }
        __syncthreads();
        // ---- G: LSTM pointwise ----
        for (int idx = tid; idx < NITEMS * 128; idx += NTHREADS) {
            int m = idx >> 7, u = idx & 127;
            float gi = sm.gates[m][u];
            float gf = sm.gates[m][128 + u];
            float gg = sm.gates[m][256 + u];
            float go = sm.gates[m][384 + u];
            float A  = sigmoid_ref(gf) * sm.c[m][u];
            float Bv = sigmoid_ref(gi) * tanh_ref(gg);
            float cn = A + Bv;
            sm.c[m][u] = cn;
            sm.h[m][u] = sigmoid_ref(go) * tanh_ref(cn);
        }
        __syncthreads();
    }

    for (int idx = tid; idx < NITEMS * 128; idx += NTHREADS)
        out[(size_t)item0 * 128 + idx] = sm.h[idx >> 7][idx & 127];
}

extern "C" void kernel_launch(void* const* d_in, const int* in_sizes, int n_in,
                              void* d_out, int out_size, void* d_ws, size_t ws_size,
                              hipStream_t stream)
{
    const float* img = (const float*)d_in[0];
    const float* Wih = (const float*)d_in[1];
    const float* Whh = (const float*)d_in[2];
    const float* bih = (const float*)d_in[3];
    const float* bhh = (const float*)d_in[4];
    const float* Wg  = (const float*)d_in[5];
    const float* bg  = (const float*)d_in[6];
    float* out = (float*)d_out;
    (void)d_ws; (void)ws_size; (void)n_in; (void)out_size;

    int B = in_sizes[0] / (2 * 64 * 64);   // 4096
    arc_main<<<B / NITEMS, NTHREADS, 0, stream>>>(img, Wih, Whh, bih, bhh, Wg, bg, out);
}

// Round 4
// 2068.125 us; speedup vs baseline: 1.6510x; 1.6510x over previous
//
#include <hip/hip_runtime.h>
#include <math.h>

// ARC / DRAW-style attention LSTM. B=4096 items, 16 steps, HID=128, 8x8 glimpse.
// Round 3: same arithmetic order as the passing round-2 kernel, restructured for
// throughput: fp32 transcendentals, 8 items/512 threads/block (2 blocks/CU),
// wave-per-item glimpse phase with broadcast F reads, register-blocked gate GEMM
// with broadcast x/h reads, padded LDS strides (conflict-free).
#define NITEMS 8
#define NTHREADS 512

// LDS offsets (floats). Total 15232 floats = 60928 B -> 2 blocks/CU.
#define OFF_H    0        // h[8][132]  (padded stride)
#define OFF_C    1056     // c[8][128]
#define OFF_GP   2080     // gp[8][3]
#define OFF_AUX  2104     // aux[8][5]: delt, gam, pg, ctrH, ctrW
#define OFF_S    2144     // S[8][2][8] normalizer sums (+1e-4)
#define OFF_F    2272     // FhT[8][64][8] then FwT[8][64][8]  (32 KB)
#define OFF_FW   6368     // = OFF_F + 4096
#define OFF_GATES OFF_F   // gates[8][512] aliases F (F dead after phase E)
#define OFF_T1   10464    // t1[8][8][66] (padded stride 66)
#define OFF_X    14688    // x[8][68]     (padded stride 68)
#define LDS_FLOATS 15232

__device__ __forceinline__ float sigf(float v) {
    float e = expf(-v);
    return 1.0f / (1.0f + e);
}

__global__ __launch_bounds__(NTHREADS) void arc_main(
    const float* __restrict__ img,    // (B,2,64,64)
    const float* __restrict__ Wih,    // (512,64)
    const float* __restrict__ Whh,    // (512,128)
    const float* __restrict__ bih,    // (512,)
    const float* __restrict__ bhh,    // (512,)
    const float* __restrict__ Wg,     // (3,128)
    const float* __restrict__ bg,     // (3,)
    float* __restrict__ out)          // (B,128)
{
    #pragma clang fp contract(off)
    __shared__ float smem[LDS_FLOATS];
    float* h_s   = smem + OFF_H;
    float* c_s   = smem + OFF_C;
    float* gp_s  = smem + OFF_GP;
    float* aux_s = smem + OFF_AUX;
    float* S_s   = smem + OFF_S;
    float* F_s   = smem + OFF_F;     // FhT: [m][i][tt] stride 512/8/1
    float* Fw_s  = smem + OFF_FW;    // FwT: [m][i][tt]
    float* g_s   = smem + OFF_GATES; // gates[m][512] (alias of F_s)
    float* t1_s  = smem + OFF_T1;    // [m][tt][66]
    float* x_s   = smem + OFF_X;     // [m][68]

    const int tid  = threadIdx.x;
    const int wid  = tid >> 6;       // wave id == item id (phase D)
    const int lane = tid & 63;
    const int item0 = blockIdx.x * NITEMS;

    for (int i = tid; i < NITEMS * 132; i += NTHREADS) h_s[i] = 0.f;
    for (int i = tid; i < NITEMS * 128; i += NTHREADS) c_s[i] = 0.f;
    __syncthreads();

    const float* img_item = img + (size_t)(item0 + wid) * 8192;

    for (int t = 0; t < 16; ++t) {
        // ---- A: gp[m][r] = tanh( sum_k h[m][k]*Wg[r][k] + bg[r] ) ----
        if (tid < NITEMS * 3) {
            int m = tid / 3, r = tid % 3;
            const float* hh = h_s + m * 132;
            const float* w  = Wg + r * 128;
            float acc = 0.f;
            for (int k = 0; k < 128; ++k) acc = fmaf(hh[k], w[k], acc);
            acc = acc + bg[r];
            gp_s[m * 3 + r] = tanhf(acc);
        }
        __syncthreads();
        // ---- A2: per-item scalars (identical formula order to round 2) ----
        if (tid < NITEMS) {
            int m = tid;
            float g0 = gp_s[m*3+0], g1 = gp_s[m*3+1], g2 = gp_s[m*3+2];
            float ad   = fabsf(g2);
            float t2   = 2.0f * ad;
            float e    = 1.0f - t2;
            float gam  = expf(e);
            float oma  = 1.0f - ad;
            float delt = 8.0f * oma;
            float pg   = 3.14159274101257324f * gam;
            float c0p  = g0 + 1.0f;
            float ctrH = (63.0f * c0p) * 0.5f;
            float c1p  = g1 + 1.0f;
            float ctrW = (63.0f * c1p) * 0.5f;
            aux_s[m*5+0] = delt; aux_s[m*5+1] = gam; aux_s[m*5+2] = pg;
            aux_s[m*5+3] = ctrH; aux_s[m*5+4] = ctrW;
        }
        __syncthreads();
        // ---- B: raw filter values, stored transposed FT[m][i][tt] ----
        for (int idx = tid; idx < NITEMS * 2 * 8 * 64; idx += NTHREADS) {
            int m    = idx >> 10;
            int bank = (idx >> 9) & 1;
            int tt   = (idx >> 6) & 7;
            int i    = idx & 63;
            float delt = aux_s[m*5+0], gam = aux_s[m*5+1], pg = aux_s[m*5+2];
            float ctr  = aux_s[m*5+3+bank];
            float gp_off = (float)tt - 3.5f;
            float dterm  = delt * gp_off;
            float gq     = ctr + dterm;
            float num    = (float)i - gq;
            float d      = num / gam;
            float dd     = d * d;
            float opdd   = 1.0f + dd;
            float den    = pg * opdd;
            smem[OFF_F + bank*4096 + m*512 + i*8 + tt] = 1.0f / den;
        }
        __syncthreads();
        // ---- C1: normalizer sums, numpy pairwise-stripe order (as round 2) ----
        if (tid < NITEMS * 16) {
            int m = tid >> 4, bank = (tid >> 3) & 1, tt = tid & 7;
            const float* fb = smem + OFF_F + bank*4096 + m*512 + tt;  // stride 8 over i
            float r0=fb[0*8], r1=fb[1*8], r2=fb[2*8], r3=fb[3*8];
            float r4=fb[4*8], r5=fb[5*8], r6=fb[6*8], r7=fb[7*8];
            for (int i = 8; i < 64; i += 8) {
                r0 += fb[(i)*8];   r1 += fb[(i+1)*8]; r2 += fb[(i+2)*8]; r3 += fb[(i+3)*8];
                r4 += fb[(i+4)*8]; r5 += fb[(i+5)*8]; r6 += fb[(i+6)*8]; r7 += fb[(i+7)*8];
            }
            float s = ((r0 + r1) + (r2 + r3)) + ((r4 + r5) + (r6 + r7));
            S_s[m*16 + bank*8 + tt] = s + 1e-4f;
        }
        __syncthreads();
        // ---- C2: normalize F in place ----
        for (int idx = tid; idx < NITEMS * 2 * 8 * 64; idx += NTHREADS) {
            int m    = idx >> 10;
            int bank = (idx >> 9) & 1;
            int tt   = (idx >> 6) & 7;
            int i    = idx & 63;
            smem[OFF_F + bank*4096 + m*512 + i*8 + tt] /= S_s[m*16 + bank*8 + tt];
        }
        __syncthreads();
        // ---- D: t1[m][tt][w] = sum_h FhT[m][h][tt] * img[m][h][w] ----
        // wave = item, lane = w; F reads are wave-uniform float4 broadcasts.
        {
            const float* ip = img_item + (t & 1) * 4096;
            const float* Fm = F_s + wid * 512;
            float a0=0,a1=0,a2=0,a3=0,a4=0,a5=0,a6=0,a7=0;
            #pragma unroll 4
            for (int hh = 0; hh < 64; ++hh) {
                float iv = ip[hh * 64 + lane];                  // coalesced 256B
                float4 f0 = *(const float4*)(Fm + hh*8);        // broadcast
                float4 f1 = *(const float4*)(Fm + hh*8 + 4);
                a0 = fmaf(f0.x, iv, a0); a1 = fmaf(f0.y, iv, a1);
                a2 = fmaf(f0.z, iv, a2); a3 = fmaf(f0.w, iv, a3);
                a4 = fmaf(f1.x, iv, a4); a5 = fmaf(f1.y, iv, a5);
                a6 = fmaf(f1.z, iv, a6); a7 = fmaf(f1.w, iv, a7);
            }
            float* t1p = t1_s + wid * 528;                      // item stride 8*66
            t1p[0*66+lane]=a0; t1p[1*66+lane]=a1; t1p[2*66+lane]=a2; t1p[3*66+lane]=a3;
            t1p[4*66+lane]=a4; t1p[5*66+lane]=a5; t1p[6*66+lane]=a6; t1p[7*66+lane]=a7;
        }
        __syncthreads();
        // ---- E: x[m][tr*8+s] = sum_w t1[m][tr][w] * FwT[m][w][s] ----
        {
            int m = tid >> 6, rem = tid & 63;
            int tr = rem >> 3, s = rem & 7;
            const float* trow = t1_s + m*528 + tr*66;
            const float* fwp  = Fw_s + m*512 + s;               // stride 8 over w
            float acc = 0.f;
            #pragma unroll 8
            for (int w = 0; w < 64; ++w) acc = fmaf(trow[w], fwp[w*8], acc);
            x_s[m*68 + rem] = acc;
        }
        __syncthreads();
        // ---- F: gates[m][j] = ((x.Wih_j + bih_j) + h.Whh_j) + bhh_j ----
        // thread = 4 gates (j0..j0+3) x 2 items (m0,m0+1); m wave-uniform.
        {
            const int mg = tid >> 7;          // 0..3 -> items m0=2*mg, m0+1
            const int jg = tid & 127;         // j0 = 4*jg
            const int m0 = mg * 2, j0 = jg * 4;
            float ax[4][2], ah[4][2];
            #pragma unroll
            for (int jj = 0; jj < 4; ++jj) { ax[jj][0]=0.f; ax[jj][1]=0.f; ah[jj][0]=0.f; ah[jj][1]=0.f; }
            const float* x0 = x_s + m0*68;
            const float* x1 = x_s + (m0+1)*68;
            #pragma unroll 4
            for (int kk = 0; kk < 64; kk += 4) {
                float4 xv0 = *(const float4*)(x0 + kk);         // broadcast
                float4 xv1 = *(const float4*)(x1 + kk);
                #pragma unroll
                for (int jj = 0; jj < 4; ++jj) {
                    float4 w = *(const float4*)(Wih + (j0+jj)*64 + kk);
                    ax[jj][0] = fmaf(xv0.x, w.x, ax[jj][0]);
                    ax[jj][0] = fmaf(xv0.y, w.y, ax[jj][0]);
                    ax[jj][0] = fmaf(xv0.z, w.z, ax[jj][0]);
                    ax[jj][0] = fmaf(xv0.w, w.w, ax[jj][0]);
                    ax[jj][1] = fmaf(xv1.x, w.x, ax[jj][1]);
                    ax[jj][1] = fmaf(xv1.y, w.y, ax[jj][1]);
                    ax[jj][1] = fmaf(xv1.z, w.z, ax[jj][1]);
                    ax[jj][1] = fmaf(xv1.w, w.w, ax[jj][1]);
                }
            }
            const float* h0 = h_s + m0*132;
            const float* h1 = h_s + (m0+1)*132;
            #pragma unroll 4
            for (int kk = 0; kk < 128; kk += 4) {
                float4 hv0 = *(const float4*)(h0 + kk);         // broadcast
                float4 hv1 = *(const float4*)(h1 + kk);
                #pragma unroll
                for (int jj = 0; jj < 4; ++jj) {
                    float4 w = *(const float4*)(Whh + (j0+jj)*128 + kk);
                    ah[jj][0] = fmaf(hv0.x, w.x, ah[jj][0]);
                    ah[jj][0] = fmaf(hv0.y, w.y, ah[jj][0]);
                    ah[jj][0] = fmaf(hv0.z, w.z, ah[jj][0]);
                    ah[jj][0] = fmaf(hv0.w, w.w, ah[jj][0]);
                    ah[jj][1] = fmaf(hv1.x, w.x, ah[jj][1]);
                    ah[jj][1] = fmaf(hv1.y, w.y, ah[jj][1]);
                    ah[jj][1] = fmaf(hv1.z, w.z, ah[jj][1]);
                    ah[jj][1] = fmaf(hv1.w, w.w, ah[jj][1]);
                }
            }
            #pragma unroll
            for (int jj = 0; jj < 4; ++jj) {
                float bi = bih[j0+jj], bh = bhh[j0+jj];
                g_s[(m0  )*512 + j0+jj] = ((ax[jj][0] + bi) + ah[jj][0]) + bh;
                g_s[(m0+1)*512 + j0+jj] = ((ax[jj][1] + bi) + ah[jj][1]) + bh;
            }
        }
        __syncthreads();
        // ---- G: LSTM pointwise (fp32 transcendentals) ----
        #pragma unroll
        for (int rep = 0; rep < 2; ++rep) {
            int idx = tid + rep * NTHREADS;   // 1024 = 8 items * 128
            int m = idx >> 7, uu = idx & 127;
            const float* gr = g_s + m * 512;
            float gi = gr[uu], gf = gr[128+uu], gg = gr[256+uu], go = gr[384+uu];
            float A  = sigf(gf) * c_s[m*128 + uu];
            float Bv = sigf(gi) * tanhf(gg);
            float cn = A + Bv;
            c_s[m*128 + uu] = cn;
            h_s[m*132 + uu] = sigf(go) * tanhf(cn);
        }
        __syncthreads();
    }

    for (int idx = tid; idx < NITEMS * 128; idx += NTHREADS)
        out[(size_t)item0 * 128 + idx] = h_s[(idx >> 7)*132 + (idx & 127)];
}

extern "C" void kernel_launch(void* const* d_in, const int* in_sizes, int n_in,
                              void* d_out, int out_size, void* d_ws, size_t ws_size,
                              hipStream_t stream)
{
    const float* img = (const float*)d_in[0];
    const float* Wih = (const float*)d_in[1];
    const float* Whh = (const float*)d_in[2];
    const float* bih = (const float*)d_in[3];
    const float* bhh = (const float*)d_in[4];
    const float* Wg  = (const float*)d_in[5];
    const float* bg  = (const float*)d_in[6];
    float* out = (float*)d_out;
    (void)d_ws; (void)ws_size; (void)n_in; (void)out_size;

    int B = in_sizes[0] / (2 * 64 * 64);   // 4096
    arc_main<<<B / NITEMS, NTHREADS, 0, stream>>>(img, Wih, Whh, bih, bhh, Wg, bg, out);
}

// Round 5
// 735.938 us; speedup vs baseline: 4.6396x; 2.8102x over previous
//
#include <hip/hip_runtime.h>
#include <math.h>

// ARC / DRAW-style attention LSTM. B=4096 items, 16 steps, HID=128, 8x8 glimpse.
// Round 4: same arithmetic order as the passing round-3 kernel for all sensitive
// phases. Changes: (1) phase F -> thread=gate, acc[8] items, 1x weight read per
// block-step (was 4x); (2) LDS cut to 43.6KB (Fh/Fw share one region, gates alias
// t1, normalizers folded as output-side reciprocal multiplies); (3) filter writes
// contiguous per-thread (kills the 16-way bank conflicts in old phase B/C2).
#define NITEMS 8
#define NTHREADS 512

// LDS offsets (floats). Total 11168 floats = 44672 B -> 2+ blocks/CU.
#define OFF_R1   0        // 4096: raw F (Fh for phases B1/D, then Fw for B2/E)
#define OFF_R2   4096     // 4224: t1[8][8][66] (D/E), then gates[8][512] (F/G)
#define OFF_H    8320     // h[8][132]
#define OFF_C    9376     // c[8][128]
#define OFF_X    10400    // x[8][72]  (stride 72: 16B-aligned rows)
#define OFF_GP   10976    // gp[8][3]
#define OFF_AUX  11000    // aux[8][5]: delt, gam, pg, ctrH, ctrW
#define OFF_RS   11040    // rs[8][16]: 1/(S+1e-4), [0..7]=h, [8..15]=w
#define LDS_FLOATS 11168

__device__ __forceinline__ float sigf(float v) {
    float e = expf(-v);
    return 1.0f / (1.0f + e);
}

__global__ __launch_bounds__(NTHREADS) void arc_main(
    const float* __restrict__ img,    // (B,2,64,64)
    const float* __restrict__ Wih,    // (512,64)
    const float* __restrict__ Whh,    // (512,128)
    const float* __restrict__ bih,    // (512,)
    const float* __restrict__ bhh,    // (512,)
    const float* __restrict__ Wg,     // (3,128)
    const float* __restrict__ bg,     // (3,)
    float* __restrict__ out)          // (B,128)
{
    #pragma clang fp contract(off)
    __shared__ float smem[LDS_FLOATS];
    float* R1   = smem + OFF_R1;     // raw filter values [m][i][8]
    float* R2   = smem + OFF_R2;     // t1 [m][tt][66] -> gates [m][512]
    float* h_s  = smem + OFF_H;
    float* c_s  = smem + OFF_C;
    float* x_s  = smem + OFF_X;
    float* gp_s = smem + OFF_GP;
    float* aux_s= smem + OFF_AUX;
    float* rs_s = smem + OFF_RS;

    const int tid  = threadIdx.x;
    const int wid  = tid >> 6;       // wave id == item id (phase D)
    const int lane = tid & 63;
    const int item0 = blockIdx.x * NITEMS;

    for (int i = tid; i < NITEMS * 132; i += NTHREADS) h_s[i] = 0.f;
    for (int i = tid; i < NITEMS * 128; i += NTHREADS) c_s[i] = 0.f;
    __syncthreads();

    const float* img_item = img + (size_t)(item0 + wid) * 8192;

    for (int t = 0; t < 16; ++t) {
        // ---- A: gp[m][r] = tanh( sum_k h[m][k]*Wg[r][k] + bg[r] ) ----
        if (tid < NITEMS * 3) {
            int m = tid / 3, r = tid % 3;
            const float* hh = h_s + m * 132;
            const float* w  = Wg + r * 128;
            float acc = 0.f;
            for (int k = 0; k < 128; ++k) acc = fmaf(hh[k], w[k], acc);
            acc = acc + bg[r];
            gp_s[m * 3 + r] = tanhf(acc);
        }
        __syncthreads();
        // ---- A2: per-item scalars (identical formula order to rounds 2/3) ----
        if (tid < NITEMS) {
            int m = tid;
            float g0 = gp_s[m*3+0], g1 = gp_s[m*3+1], g2 = gp_s[m*3+2];
            float ad   = fabsf(g2);
            float t2   = 2.0f * ad;
            float e    = 1.0f - t2;
            float gam  = expf(e);
            float oma  = 1.0f - ad;
            float delt = 8.0f * oma;
            float pg   = 3.14159274101257324f * gam;
            float c0p  = g0 + 1.0f;
            float ctrH = (63.0f * c0p) * 0.5f;
            float c1p  = g1 + 1.0f;
            float ctrW = (63.0f * c1p) * 0.5f;
            aux_s[m*5+0] = delt; aux_s[m*5+1] = gam; aux_s[m*5+2] = pg;
            aux_s[m*5+3] = ctrH; aux_s[m*5+4] = ctrW;
        }
        __syncthreads();

        // ================= H-bank: B1 (raw Fh), C1h (rs_h), D =================
        // ---- B1: thread (m,i) computes all 8 tt of raw Fh; contiguous writes ----
        {
            int m = tid >> 6, i = tid & 63;
            float delt = aux_s[m*5+0], gam = aux_s[m*5+1], pg = aux_s[m*5+2];
            float ctr  = aux_s[m*5+3];
            float v[8];
            #pragma unroll
            for (int tt = 0; tt < 8; ++tt) {
                float gp_off = (float)tt - 3.5f;
                float dterm  = delt * gp_off;
                float gq     = ctr + dterm;
                float num    = (float)i - gq;
                float d      = num / gam;
                float dd     = d * d;
                float opdd   = 1.0f + dd;
                float den    = pg * opdd;
                v[tt] = 1.0f / den;
            }
            float4* p = (float4*)(R1 + m*512 + i*8);
            p[0] = make_float4(v[0], v[1], v[2], v[3]);
            p[1] = make_float4(v[4], v[5], v[6], v[7]);
        }
        __syncthreads();
        // ---- C1h: rs_h[m][tt] = 1/(stripe_sum_i Fh + 1e-4) ----
        if (tid < 64) {
            int m = tid >> 3, tt = tid & 7;
            const float* fb = R1 + m*512 + tt;   // stride 8 over i
            float r0=fb[0*8], r1=fb[1*8], r2=fb[2*8], r3=fb[3*8];
            float r4=fb[4*8], r5=fb[5*8], r6=fb[6*8], r7=fb[7*8];
            for (int i = 8; i < 64; i += 8) {
                r0 += fb[(i)*8];   r1 += fb[(i+1)*8]; r2 += fb[(i+2)*8]; r3 += fb[(i+3)*8];
                r4 += fb[(i+4)*8]; r5 += fb[(i+5)*8]; r6 += fb[(i+6)*8]; r7 += fb[(i+7)*8];
            }
            float s = ((r0 + r1) + (r2 + r3)) + ((r4 + r5) + (r6 + r7));
            rs_s[m*16 + tt] = 1.0f / (s + 1e-4f);
        }
        __syncthreads();
        // ---- D: t1[m][tt][w] = rs_h[tt] * sum_h Fh_raw[m][h][tt]*img[m][h][w] ----
        {
            const float* ip = img_item + (t & 1) * 4096;
            const float* Fm = R1 + wid * 512;
            float a0=0,a1=0,a2=0,a3=0,a4=0,a5=0,a6=0,a7=0;
            #pragma unroll 4
            for (int hh = 0; hh < 64; ++hh) {
                float iv = ip[hh * 64 + lane];              // coalesced 256B
                float4 f0 = *(const float4*)(Fm + hh*8);    // broadcast
                float4 f1 = *(const float4*)(Fm + hh*8 + 4);
                a0 = fmaf(f0.x, iv, a0); a1 = fmaf(f0.y, iv, a1);
                a2 = fmaf(f0.z, iv, a2); a3 = fmaf(f0.w, iv, a3);
                a4 = fmaf(f1.x, iv, a4); a5 = fmaf(f1.y, iv, a5);
                a6 = fmaf(f1.z, iv, a6); a7 = fmaf(f1.w, iv, a7);
            }
            const float* rsm = rs_s + wid*16;
            a0 *= rsm[0]; a1 *= rsm[1]; a2 *= rsm[2]; a3 *= rsm[3];
            a4 *= rsm[4]; a5 *= rsm[5]; a6 *= rsm[6]; a7 *= rsm[7];
            float* t1p = R2 + wid * 528;                    // rows stride 66
            t1p[0*66+lane]=a0; t1p[1*66+lane]=a1; t1p[2*66+lane]=a2; t1p[3*66+lane]=a3;
            t1p[4*66+lane]=a4; t1p[5*66+lane]=a5; t1p[6*66+lane]=a6; t1p[7*66+lane]=a7;
        }
        __syncthreads();

        // ================= W-bank: B2 (raw Fw over R1), C1w, E =================
        {
            int m = tid >> 6, i = tid & 63;
            float delt = aux_s[m*5+0], gam = aux_s[m*5+1], pg = aux_s[m*5+2];
            float ctr  = aux_s[m*5+4];
            float v[8];
            #pragma unroll
            for (int tt = 0; tt < 8; ++tt) {
                float gp_off = (float)tt - 3.5f;
                float dterm  = delt * gp_off;
                float gq     = ctr + dterm;
                float num    = (float)i - gq;
                float d      = num / gam;
                float dd     = d * d;
                float opdd   = 1.0f + dd;
                float den    = pg * opdd;
                v[tt] = 1.0f / den;
            }
            float4* p = (float4*)(R1 + m*512 + i*8);
            p[0] = make_float4(v[0], v[1], v[2], v[3]);
            p[1] = make_float4(v[4], v[5], v[6], v[7]);
        }
        __syncthreads();
        if (tid < 64) {
            int m = tid >> 3, tt = tid & 7;
            const float* fb = R1 + m*512 + tt;
            float r0=fb[0*8], r1=fb[1*8], r2=fb[2*8], r3=fb[3*8];
            float r4=fb[4*8], r5=fb[5*8], r6=fb[6*8], r7=fb[7*8];
            for (int i = 8; i < 64; i += 8) {
                r0 += fb[(i)*8];   r1 += fb[(i+1)*8]; r2 += fb[(i+2)*8]; r3 += fb[(i+3)*8];
                r4 += fb[(i+4)*8]; r5 += fb[(i+5)*8]; r6 += fb[(i+6)*8]; r7 += fb[(i+7)*8];
            }
            float s = ((r0 + r1) + (r2 + r3)) + ((r4 + r5) + (r6 + r7));
            rs_s[m*16 + 8 + tt] = 1.0f / (s + 1e-4f);
        }
        __syncthreads();
        // ---- E: x[m][tr*8+s] = rs_w[s] * sum_w t1[m][tr][w] * Fw_raw[m][w][s] ----
        {
            int m = tid >> 6, rem = tid & 63;
            int tr = rem >> 3, s = rem & 7;
            const float* trow = R2 + m*528 + tr*66;
            const float* fwp  = R1 + m*512 + s;             // stride 8 over w
            float acc = 0.f;
            #pragma unroll 8
            for (int w = 0; w < 64; ++w) acc = fmaf(trow[w], fwp[w*8], acc);
            acc *= rs_s[m*16 + 8 + s];
            x_s[m*72 + rem] = acc;
        }
        __syncthreads();

        // ---- F: gates[m][j]; thread = gate j, acc over 8 items (1x weight read) ----
        {
            const int j = tid;
            float bi = bih[j], bh = bhh[j];
            float acc[8];
            #pragma unroll
            for (int mm = 0; mm < 8; ++mm) acc[mm] = 0.f;
            const float4* wr = (const float4*)(Wih + j * 64);
            #pragma unroll 4
            for (int q = 0; q < 16; ++q) {
                float4 w = wr[q];
                #pragma unroll
                for (int mm = 0; mm < 8; ++mm) {
                    float4 xv = *(const float4*)(x_s + mm*72 + q*4);   // broadcast
                    acc[mm] = fmaf(xv.x, w.x, acc[mm]);
                    acc[mm] = fmaf(xv.y, w.y, acc[mm]);
                    acc[mm] = fmaf(xv.z, w.z, acc[mm]);
                    acc[mm] = fmaf(xv.w, w.w, acc[mm]);
                }
            }
            float ach[8];
            #pragma unroll
            for (int mm = 0; mm < 8; ++mm) ach[mm] = 0.f;
            const float4* vr = (const float4*)(Whh + j * 128);
            #pragma unroll 4
            for (int q = 0; q < 32; ++q) {
                float4 w = vr[q];
                #pragma unroll
                for (int mm = 0; mm < 8; ++mm) {
                    float4 hv = *(const float4*)(h_s + mm*132 + q*4);  // broadcast
                    ach[mm] = fmaf(hv.x, w.x, ach[mm]);
                    ach[mm] = fmaf(hv.y, w.y, ach[mm]);
                    ach[mm] = fmaf(hv.z, w.z, ach[mm]);
                    ach[mm] = fmaf(hv.w, w.w, ach[mm]);
                }
            }
            #pragma unroll
            for (int mm = 0; mm < 8; ++mm)
                R2[mm*512 + j] = ((acc[mm] + bi) + ach[mm]) + bh;      // gates alias t1
        }
        __syncthreads();
        // ---- G: LSTM pointwise ----
        #pragma unroll
        for (int rep = 0; rep < 2; ++rep) {
            int idx = tid + rep * NTHREADS;   // 1024 = 8 items * 128
            int m = idx >> 7, uu = idx & 127;
            const float* gr = R2 + m * 512;
            float gi = gr[uu], gf = gr[128+uu], gg = gr[256+uu], go = gr[384+uu];
            float A  = sigf(gf) * c_s[m*128 + uu];
            float Bv = sigf(gi) * tanhf(gg);
            float cn = A + Bv;
            c_s[m*128 + uu] = cn;
            h_s[m*132 + uu] = sigf(go) * tanhf(cn);
        }
        __syncthreads();
    }

    for (int idx = tid; idx < NITEMS * 128; idx += NTHREADS)
        out[(size_t)item0 * 128 + idx] = h_s[(idx >> 7)*132 + (idx & 127)];
}

extern "C" void kernel_launch(void* const* d_in, const int* in_sizes, int n_in,
                              void* d_out, int out_size, void* d_ws, size_t ws_size,
                              hipStream_t stream)
{
    const float* img = (const float*)d_in[0];
    const float* Wih = (const float*)d_in[1];
    const float* Whh = (const float*)d_in[2];
    const float* bih = (const float*)d_in[3];
    const float* bhh = (const float*)d_in[4];
    const float* Wg  = (const float*)d_in[5];
    const float* bg  = (const float*)d_in[6];
    float* out = (float*)d_out;
    (void)d_ws; (void)ws_size; (void)n_in; (void)out_size;

    int B = in_sizes[0] / (2 * 64 * 64);   // 4096
    arc_main<<<B / NITEMS, NTHREADS, 0, stream>>>(img, Wih, Whh, bih, bhh, Wg, bg, out);
}